// Round 5
// baseline (31.811 us; speedup 1.0000x reference)
//
#include <hip/hip_runtime.h>

#define HW (512 * 512)           // floats per channel
#define NCH 48                   // L*C = 16*3 channels
#define CF4 (HW / 4)             // 65536 float4 per channel
#define NF4 (NCH * CF4)          // 3,145,728 float4 total
#define GRID1 2048               // = exactly 8 blocks/CU on 256 CUs
#define TPB1 256
#define F4PB (NF4 / GRID1)       // 1536 float4 per block
#define IT1 (F4PB / TPB1)        // 6 iterations per thread, exact
#define V_EPS 1e-5

// Kernel 1: flat decomposition for 32 waves/CU. Each block owns a contiguous
// 1536-float4 slab that straddles at most ONE channel boundary; partial sums
// are kept in dual (lo/hi) accumulator sets selected per element.
__global__ __launch_bounds__(TPB1) void smse_partials(
    const float* __restrict__ correct,
    const float* __restrict__ estimate,
    const float* __restrict__ mask,
    float4* __restrict__ partials)   // [GRID1 * 2]: {lo, hi} per block
{
    const int b    = blockIdx.x;
    const int base = b * F4PB;
    const int chLo = base >> 16;     // base / CF4

    const float4* __restrict__ c4 = (const float4*)correct;
    const float4* __restrict__ e4 = (const float4*)estimate;
    const float4* __restrict__ m4 = (const float4*)mask;

    float lo0 = 0.f, lo1 = 0.f, lo2 = 0.f, lo3 = 0.f;
    float hi0 = 0.f, hi1 = 0.f, hi2 = 0.f, hi3 = 0.f;

    int i = base + threadIdx.x;
    #pragma unroll
    for (int k = 0; k < IT1; ++k, i += TPB1) {
        float4 c = c4[i];
        float4 e = e4[i];
        float4 m = m4[i];
        // Per-float4 sums (all 4 components share one channel).
        float s0 = 0.f, s1 = 0.f, s2 = 0.f, s3 = 0.f, em;
        em = e.x * m.x; s0 += e.x * em; s1 += c.x * em; s2 += c.x * c.x * m.x; s3 += m.x;
        em = e.y * m.y; s0 += e.y * em; s1 += c.y * em; s2 += c.y * c.y * m.y; s3 += m.y;
        em = e.z * m.z; s0 += e.z * em; s1 += c.z * em; s2 += c.z * c.z * m.z; s3 += m.z;
        em = e.w * m.w; s0 += e.w * em; s1 += c.w * em; s2 += c.w * c.w * m.w; s3 += m.w;
        // Channel select: fma into lo or hi set.
        float fhi = ((i >> 16) != chLo) ? 1.f : 0.f;
        float flo = 1.f - fhi;
        lo0 += flo * s0; lo1 += flo * s1; lo2 += flo * s2; lo3 += flo * s3;
        hi0 += fhi * s0; hi1 += fhi * s1; hi2 += fhi * s2; hi3 += fhi * s3;
    }

    // Wave64 butterfly reduce of the 8 accumulators.
    #pragma unroll
    for (int off = 32; off > 0; off >>= 1) {
        lo0 += __shfl_down(lo0, off); lo1 += __shfl_down(lo1, off);
        lo2 += __shfl_down(lo2, off); lo3 += __shfl_down(lo3, off);
        hi0 += __shfl_down(hi0, off); hi1 += __shfl_down(hi1, off);
        hi2 += __shfl_down(hi2, off); hi3 += __shfl_down(hi3, off);
    }

    __shared__ float4 redLo[TPB1 / 64];
    __shared__ float4 redHi[TPB1 / 64];
    const int wave = threadIdx.x >> 6;
    const int lane = threadIdx.x & 63;
    if (lane == 0) {
        redLo[wave] = make_float4(lo0, lo1, lo2, lo3);
        redHi[wave] = make_float4(hi0, hi1, hi2, hi3);
    }
    __syncthreads();

    if (threadIdx.x == 0) {
        float4 slo = redLo[0], shi = redHi[0];
        #pragma unroll
        for (int w = 1; w < TPB1 / 64; ++w) {
            float4 a = redLo[w], b2 = redHi[w];
            slo.x += a.x;  slo.y += a.y;  slo.z += a.z;  slo.w += a.w;
            shi.x += b2.x; shi.y += b2.y; shi.z += b2.z; shi.w += b2.w;
        }
        partials[2 * b]     = slo;
        partials[2 * b + 1] = shi;
    }
}

// Kernel 2: per channel, gather lo/hi slots from the blocks overlapping that
// channel (span <= 44 blocks), 8 threads/channel, fixed order (deterministic).
__global__ __launch_bounds__(384) void smse_final(
    const float4* __restrict__ partials,
    float* __restrict__ out)
{
    const int t  = threadIdx.x;   // 384 = 48 channels * 8
    const int ch = t >> 3;
    const int k  = t & 7;

    const int bstart = (ch * CF4) / F4PB;
    const int bend   = ((ch + 1) * CF4 - 1) / F4PB;

    float sx = 0.f, sy = 0.f, sz = 0.f, sw = 0.f;
    #pragma unroll
    for (int j = 0; j < 6; ++j) {           // 8 threads * 6 = 48 >= max span 44
        int b = bstart + k + 8 * j;
        if (b <= bend) {
            int cl = (b * F4PB) >> 16;
            int chh = (b * F4PB + F4PB - 1) >> 16;
            float4 lo = partials[2 * b];
            float4 hi = partials[2 * b + 1];
            if (cl == ch)  { sx += lo.x; sy += lo.y; sz += lo.z; sw += lo.w; }
            if (chh == ch) { sx += hi.x; sy += hi.y; sz += hi.z; sw += hi.w; }
        }
    }

    // Reduce across the 8 lanes of this channel.
    #pragma unroll
    for (int off = 4; off > 0; off >>= 1) {
        sx += __shfl_down(sx, off, 8);
        sy += __shfl_down(sy, off, 8);
        sz += __shfl_down(sz, off, 8);
        sw += __shfl_down(sw, off, 8);
    }

    __shared__ float chval[64];
    if (t < 64) chval[t] = 0.f;
    __syncthreads();
    if (k == 0) {
        double v = sx, num = sy, cc = sz, ms = sw;
        double alpha = (v > V_EPS) ? (num / v) : 0.0;
        double err = cc - alpha * (2.0 * num - alpha * v);
        chval[ch] = (float)(err / ms);
    }
    __syncthreads();

    if (t < 64) {
        float val = chval[t];
        #pragma unroll
        for (int off = 32; off > 0; off >>= 1) val += __shfl_down(val, off);
        if (t == 0) out[0] = val / (float)NCH;
    }
}

extern "C" void kernel_launch(void* const* d_in, const int* in_sizes, int n_in,
                              void* d_out, int out_size, void* d_ws, size_t ws_size,
                              hipStream_t stream) {
    const float* correct  = (const float*)d_in[0];
    const float* estimate = (const float*)d_in[1];
    const float* mask     = (const float*)d_in[2];
    float* out = (float*)d_out;
    float4* partials = (float4*)d_ws;  // GRID1*2 float4 = 64 KiB

    smse_partials<<<GRID1, TPB1, 0, stream>>>(correct, estimate, mask, partials);
    smse_final<<<1, 384, 0, stream>>>(partials, out);
}

// Round 6
// 28.921 us; speedup vs baseline: 1.0999x; 1.0999x over previous
//
#include <hip/hip_runtime.h>

#define HW (512 * 512)
#define NCH 48              // L*C = 16*3 channels
#define BPC 32              // blocks per channel -> grid 1536 = 6/CU exactly
#define TPB 256
#define ITERS (HW / 4 / (BPC * TPB))  // = 8, exact
#define V_EPS 1e-5

// Kernel 1: per-block partial sums of {e*e*m, c*e*m, c*c*m, m} over one channel.
// R1-R5 established this is memory-system-bound: four structurally different
// bodies (ragged, 2x-unrolled MLP, this, flat 8-blk/CU) all profile 49-51 us.
__global__ __launch_bounds__(TPB) void smse_partials(
    const float* __restrict__ correct,
    const float* __restrict__ estimate,
    const float* __restrict__ mask,
    float4* __restrict__ partials)  // [NCH * BPC]
{
    const int ch  = blockIdx.x / BPC;
    const int bin = blockIdx.x % BPC;

    const float4* __restrict__ c4 = (const float4*)(correct  + (size_t)ch * HW);
    const float4* __restrict__ e4 = (const float4*)(estimate + (size_t)ch * HW);
    const float4* __restrict__ m4 = (const float4*)(mask     + (size_t)ch * HW);

    const int stride = BPC * TPB;  // 8192 float4
    int i = bin * TPB + threadIdx.x;

    float se2m = 0.f, scem = 0.f, sc2m = 0.f, sm = 0.f;
    #pragma unroll
    for (int it = 0; it < ITERS; ++it, i += stride) {
        float4 c = c4[i];
        float4 e = e4[i];
        float4 m = m4[i];
        float em;
        em = e.x * m.x; se2m += e.x * em; scem += c.x * em; sc2m += c.x * c.x * m.x; sm += m.x;
        em = e.y * m.y; se2m += e.y * em; scem += c.y * em; sc2m += c.y * c.y * m.y; sm += m.y;
        em = e.z * m.z; se2m += e.z * em; scem += c.z * em; sc2m += c.z * c.z * m.z; sm += m.z;
        em = e.w * m.w; se2m += e.w * em; scem += c.w * em; sc2m += c.w * c.w * m.w; sm += m.w;
    }

    // Wave64 butterfly reduce of the 4 accumulators.
    #pragma unroll
    for (int off = 32; off > 0; off >>= 1) {
        se2m += __shfl_down(se2m, off);
        scem += __shfl_down(scem, off);
        sc2m += __shfl_down(sc2m, off);
        sm   += __shfl_down(sm,   off);
    }

    __shared__ float4 red[TPB / 64];
    const int wave = threadIdx.x >> 6;
    const int lane = threadIdx.x & 63;
    if (lane == 0) red[wave] = make_float4(se2m, scem, sc2m, sm);
    __syncthreads();

    if (threadIdx.x == 0) {
        float4 s = red[0];
        #pragma unroll
        for (int w = 1; w < TPB / 64; ++w) {
            float4 r = red[w];
            s.x += r.x; s.y += r.y; s.z += r.z; s.w += r.w;
        }
        partials[(size_t)ch * BPC + bin] = s;
    }
}

// Kernel 2: parallel reduce. 8 threads per channel, each loads 4 float4
// partials (issued in one burst), width-8 shuffle reduce, per-channel
// formula, then one wave reduces the 48 channel values.
__global__ __launch_bounds__(384) void smse_final(
    const float4* __restrict__ partials,
    float* __restrict__ out)
{
    const int t  = threadIdx.x;   // 384 = 48 channels * 8
    const int ch = t >> 3;
    const int k  = t & 7;

    // Burst-load this thread's 4 partials (independent L2-hit loads).
    const float4* p = partials + (size_t)ch * BPC + k * 4;
    float4 a = p[0], b = p[1], c = p[2], d = p[3];
    float sx = (a.x + b.x) + (c.x + d.x);
    float sy = (a.y + b.y) + (c.y + d.y);
    float sz = (a.z + b.z) + (c.z + d.z);
    float sw = (a.w + b.w) + (c.w + d.w);

    // Reduce across the 8 lanes of this channel (lanes are contiguous in-wave).
    #pragma unroll
    for (int off = 4; off > 0; off >>= 1) {
        sx += __shfl_down(sx, off, 8);
        sy += __shfl_down(sy, off, 8);
        sz += __shfl_down(sz, off, 8);
        sw += __shfl_down(sw, off, 8);
    }

    __shared__ float chval[64];
    if (t < 64) chval[t] = 0.f;
    __syncthreads();
    if (k == 0) {
        double v = sx, num = sy, cc = sz, ms = sw;
        double alpha = (v > V_EPS) ? (num / v) : 0.0;
        double err = cc - alpha * (2.0 * num - alpha * v);
        chval[ch] = (float)(err / ms);
    }
    __syncthreads();

    if (t < 64) {
        float val = chval[t];
        #pragma unroll
        for (int off = 32; off > 0; off >>= 1) val += __shfl_down(val, off);
        if (t == 0) out[0] = val / (float)NCH;
    }
}

extern "C" void kernel_launch(void* const* d_in, const int* in_sizes, int n_in,
                              void* d_out, int out_size, void* d_ws, size_t ws_size,
                              hipStream_t stream) {
    const float* correct  = (const float*)d_in[0];
    const float* estimate = (const float*)d_in[1];
    const float* mask     = (const float*)d_in[2];
    float* out = (float*)d_out;
    float4* partials = (float4*)d_ws;  // NCH*BPC float4 = 24 KiB

    smse_partials<<<NCH * BPC, TPB, 0, stream>>>(correct, estimate, mask, partials);
    smse_final<<<1, 384, 0, stream>>>(partials, out);
}